// Round 4
// baseline (635.021 us; speedup 1.0000x reference)
//
#include <hip/hip_runtime.h>
#include <hip/hip_bf16.h>
#include <stdint.h>

// FusedLinearCrossEntropyLoss on MI355X (gfx950)
// loss = mean_i( logsumexp_j(x_i . w_j + b_j) - (x_i . w_t(i) + b_t(i)) )
//
// R9: BACK TO NO-LDS (R6 structure, best measured: 166us) + two targeted fixes
//     for its measured overheads:
//     (1) Contiguous 32B/lane chunk layout: a wave's MFMA fragment is two
//         ADJACENT dwordx4 loads -> no int4->v8i repack movs (R6: 48 v_mov/kg,
//         VALUBusy 23%).
//     (2) Explicit 2-deep register pipeline (cur/nxt, unroll-2 role swap):
//         kg g+1's 12 loads issue before kg g's MFMAs, compiler emits counted
//         vmcnt(12) -> L2 latency hides under ~550-1100cy of MFMA pipe.
//         (R6: VGPR_Count=84 => no operand pipeline, exposed L2 wait each kg.)
//     No barriers, no LDS in the K-loop (R7/R8 showed every barrier scheme
//     regresses: 2-phase 177us, 4-phase 8-wave 217us vs no-LDS 166us).
//     Register budget: 96 operand + ~27 addr (VGPR) + 128 acc (AGPR) ~= 251
//     unified <= 256 -> 2 waves/SIMD held by __launch_bounds__(256,2).
//
// Chunk layout (R9): chunk c = R*16 + g (R = 32-row block, g = 64-wide k group).
// Within chunk: lane l in 0..63, byte b in 0..31:
//   data[c*2048 + l*32 + b] = M[R*32 + (l&31)][g*64 + (l>>5)*32 + b]

typedef float f16v __attribute__((ext_vector_type(16)));
typedef int v8i __attribute__((ext_vector_type(8)));
typedef int v4i __attribute__((ext_vector_type(4)));

__device__ __forceinline__ unsigned pk_fp8(float4 v) {
  int w = 0;
  w = __builtin_amdgcn_cvt_pk_fp8_f32(v.x, v.y, w, false);  // bytes 0,1
  w = __builtin_amdgcn_cvt_pk_fp8_f32(v.z, v.w, w, true);   // bytes 2,3
  return (unsigned)w;
}

// fp32 [N x 1024] -> fp8 fragment-swizzled chunks (contiguous 32B/lane).
// One thread = 16 out bytes.
__global__ __launch_bounds__(256) void cast_swz_k(const float* __restrict__ in,
                                                  uint4* __restrict__ out,
                                                  long n16) {
  long t = (long)blockIdx.x * blockDim.x + threadIdx.x;
  long stride = (long)gridDim.x * blockDim.x;
  for (; t < n16; t += stride) {
    long o = t * 16;
    int c = (int)(o >> 11);
    int rem = (int)(o & 2047);
    int l = rem >> 5;            // lane
    int b0 = rem & 31;           // 0 or 16
    int row = (c >> 4) * 32 + (l & 31);
    int k = (c & 15) * 64 + (l >> 5) * 32 + b0;
    const float4* src = (const float4*)(in + (long)row * 1024 + k);
    uint4 oo;
    oo.x = pk_fp8(src[0]); oo.y = pk_fp8(src[1]);
    oo.z = pk_fp8(src[2]); oo.w = pk_fp8(src[3]);
    out[t] = oo;
  }
}

// One block per row: x_y[row] = x[row] . W[safe_t] + bias[safe_t]  (fp32, exact)
__global__ __launch_bounds__(256) void xy_k(const float* __restrict__ x,
                                            const float* __restrict__ w,
                                            const float* __restrict__ bias,
                                            const int* __restrict__ tgt,
                                            float* __restrict__ xy, int H, int V) {
  int row = blockIdx.x;
  int t = tgt[row];
  int st = min(max(t, 0), V - 1);
  const float4* xr = (const float4*)(x + (long)row * H);
  const float4* wr = (const float4*)(w + (long)st * H);
  float s = 0.f;
  int n4 = H >> 2;
  for (int i = threadIdx.x; i < n4; i += 256) {
    float4 a = xr[i], b = wr[i];
    s += a.x * b.x + a.y * b.y + a.z * b.z + a.w * b.w;
  }
  for (int off = 32; off; off >>= 1) s += __shfl_down(s, off, 64);
  __shared__ float sm[4];
  if ((threadIdx.x & 63) == 0) sm[threadIdx.x >> 6] = s;
  __syncthreads();
  if (threadIdx.x == 0) xy[row] = sm[0] + sm[1] + sm[2] + sm[3] + bias[st];
}

// Load one 32B/lane fragment (two adjacent dwordx4 -> v8i, no repack).
__device__ __forceinline__ v8i ldfrag(const char* p) {
  const v4i* q = (const v4i*)p;
  v4i lo = q[0];
  v4i hi = q[1];
  return __builtin_shufflevector(lo, hi, 0, 1, 2, 3, 4, 5, 6, 7);
}

// 256x128 block tile, 4 waves in 2x2; each wave 128x64 via 4x2 of 32x32x64.
// All operands loaded straight from global fragment chunks (no LDS, no
// barriers in the K-loop). Explicit cur/nxt register double-buffer.
// Epilogue: partials[by][row] = sum_cols exp(logit + bias).
__global__ __launch_bounds__(256, 2)
void gemm_sumexp(const char* __restrict__ Xf, const char* __restrict__ Wf,
                 const float* __restrict__ bias, float* __restrict__ partials,
                 int H, int BT) {
  __shared__ float rowsum[2][256];

  const int tid = threadIdx.x;
  const int w = tid >> 6, lane = tid & 63;
  const int wr = w >> 1, wc = w & 1;
  const int l32 = lane & 31, kh = lane >> 5;

  // Bijective XCD-aware swizzle (nwg = 4000, divisible by 8).
  const int nbx = gridDim.x;
  const int nwg = nbx * gridDim.y;
  const int id = blockIdx.y * nbx + blockIdx.x;
  const int swz = ((nwg & 7) == 0) ? ((id & 7) * (nwg >> 3) + (id >> 3)) : id;
  const int bx = swz % nbx;
  const int by = swz / nbx;
  const int m0 = bx * 256, n0 = by * 128;

  const int Rb = bx * 8 + wr * 4;   // A 32-row block base
  const int Nb = by * 4 + wc * 2;   // B 32-row block base

  // Fragment base pointers at kg 0.
  const char* pf[6];
#pragma unroll
  for (int mi = 0; mi < 4; mi++)
    pf[mi] = Xf + (long)(Rb + mi) * 32768 + lane * 32;
#pragma unroll
  for (int ni = 0; ni < 2; ni++)
    pf[4 + ni] = Wf + (long)(Nb + ni) * 32768 + lane * 32;

  f16v acc[4][2];
#pragma unroll
  for (int mi = 0; mi < 4; mi++)
#pragma unroll
    for (int ni = 0; ni < 2; ni++)
#pragma unroll
      for (int r = 0; r < 16; r++) acc[mi][ni][r] = 0.f;

  const int nG = H >> 6;  // 16 k-groups of 64 (even; >= 2)

  v8i cur[6], nxt[6];
  // Prologue: kg 0 into cur.
#pragma unroll
  for (int i = 0; i < 6; i++) cur[i] = ldfrag(pf[i]);

#define MFMA_BATCH(OPS)                                                       \
  {                                                                           \
    acc[0][0] = __builtin_amdgcn_mfma_scale_f32_32x32x64_f8f6f4(              \
        OPS[0], OPS[4], acc[0][0], 0, 0, 0, 127, 0, 127);                     \
    acc[1][0] = __builtin_amdgcn_mfma_scale_f32_32x32x64_f8f6f4(              \
        OPS[1], OPS[4], acc[1][0], 0, 0, 0, 127, 0, 127);                     \
    acc[2][0] = __builtin_amdgcn_mfma_scale_f32_32x32x64_f8f6f4(              \
        OPS[2], OPS[4], acc[2][0], 0, 0, 0, 127, 0, 127);                     \
    acc[3][0] = __builtin_amdgcn_mfma_scale_f32_32x32x64_f8f6f4(              \
        OPS[3], OPS[4], acc[3][0], 0, 0, 0, 127, 0, 127);                     \
    acc[0][1] = __builtin_amdgcn_mfma_scale_f32_32x32x64_f8f6f4(              \
        OPS[0], OPS[5], acc[0][1], 0, 0, 0, 127, 0, 127);                     \
    acc[1][1] = __builtin_amdgcn_mfma_scale_f32_32x32x64_f8f6f4(              \
        OPS[1], OPS[5], acc[1][1], 0, 0, 0, 127, 0, 127);                     \
    acc[2][1] = __builtin_amdgcn_mfma_scale_f32_32x32x64_f8f6f4(              \
        OPS[2], OPS[5], acc[2][1], 0, 0, 0, 127, 0, 127);                     \
    acc[3][1] = __builtin_amdgcn_mfma_scale_f32_32x32x64_f8f6f4(              \
        OPS[3], OPS[5], acc[3][1], 0, 0, 0, 127, 0, 127);                     \
  }

#pragma unroll 1
  for (int g = 0; g + 2 <= nG; g += 2) {
    // H1: issue kg g+1 loads into nxt, then compute kg g from cur.
    {
      const long ko = (long)(g + 1) * 2048;
#pragma unroll
      for (int i = 0; i < 6; i++) nxt[i] = ldfrag(pf[i] + ko);
    }
    MFMA_BATCH(cur);
    // H2: issue kg g+2 loads into cur (if any), compute kg g+1 from nxt.
    if (g + 2 < nG) {
      const long ko = (long)(g + 2) * 2048;
#pragma unroll
      for (int i = 0; i < 6; i++) cur[i] = ldfrag(pf[i] + ko);
    }
    MFMA_BATCH(nxt);
  }
#undef MFMA_BATCH

  // ---- epilogue: per-row sum of exp(logit + bias) ----
  // C/D 32x32 layout: col = lane&31, row = (reg&3) + 8*(reg>>2) + 4*(lane>>5)
  float bv[2];
  bv[0] = bias[n0 + wc * 64 + l32];
  bv[1] = bias[n0 + wc * 64 + 32 + l32];

#pragma unroll
  for (int mi = 0; mi < 4; mi++) {
    float p[16];
#pragma unroll
    for (int r = 0; r < 16; r++) p[r] = 0.f;
#pragma unroll
    for (int ni = 0; ni < 2; ni++)
#pragma unroll
      for (int r = 0; r < 16; r++) p[r] += __expf(acc[mi][ni][r] + bv[ni]);
    // reduce across the 32 columns (lanes within each 32-group)
#pragma unroll
    for (int off = 1; off < 32; off <<= 1)
#pragma unroll
      for (int r = 0; r < 16; r++) p[r] += __shfl_xor(p[r], off, 32);
    if (l32 == 0) {
#pragma unroll
      for (int r = 0; r < 16; r++)
        rowsum[wc][wr * 128 + mi * 32 + (r & 3) + 8 * (r >> 2) + 4 * kh] = p[r];
    }
  }
  __syncthreads();
  partials[(long)by * BT + m0 + tid] = rowsum[0][tid] + rowsum[1][tid];
}

// per-row: lse - x_y ; 4 threads per row for b-parallelism, 64 rows/block
__global__ __launch_bounds__(256)
void row_reduce(const float* __restrict__ partials, const float* __restrict__ xy,
                const int* __restrict__ tgt, float* __restrict__ bsum,
                float* __restrict__ bcnt, int BT, int nCB) {
  const int row = blockIdx.x * 64 + (threadIdx.x >> 2);
  const int q = threadIdx.x & 3;
  float S = 0.f;
  for (int b = q; b < nCB; b += 4) S += partials[(long)b * BT + row];
  S += __shfl_xor(S, 1, 64);
  S += __shfl_xor(S, 2, 64);
  float pr = 0.f, c = 0.f;
  if (q == 0) {
    int t = tgt[row];
    if (t != -100) { pr = logf(S) - xy[row]; c = 1.f; }
  }
  for (int off = 32; off; off >>= 1) {
    pr += __shfl_down(pr, off, 64);
    c += __shfl_down(c, off, 64);
  }
  __shared__ float sp[4], sc[4];
  if ((threadIdx.x & 63) == 0) {
    sp[threadIdx.x >> 6] = pr;
    sc[threadIdx.x >> 6] = c;
  }
  __syncthreads();
  if (threadIdx.x == 0) {
    bsum[blockIdx.x] = sp[0] + sp[1] + sp[2] + sp[3];
    bcnt[blockIdx.x] = sc[0] + sc[1] + sc[2] + sc[3];
  }
}

__global__ void finalize(const float* __restrict__ bsum, const float* __restrict__ bcnt,
                         float* __restrict__ out, int nb) {
  float s = 0.f, c = 0.f;
  for (int i = threadIdx.x; i < nb; i += 64) { s += bsum[i]; c += bcnt[i]; }
  for (int off = 32; off; off >>= 1) {
    s += __shfl_down(s, off, 64);
    c += __shfl_down(c, off, 64);
  }
  if (threadIdx.x == 0) out[0] = s / c;
}

extern "C" void kernel_launch(void* const* d_in, const int* in_sizes, int n_in,
                              void* d_out, int out_size, void* d_ws, size_t ws_size,
                              hipStream_t stream) {
  const float* x = (const float*)d_in[0];
  const int* tgt = (const int*)d_in[1];
  const float* w = (const float*)d_in[2];
  const float* bias = (const float*)d_in[3];
  float* out = (float*)d_out;

  const int BT = in_sizes[1];            // 4096
  const int V = in_sizes[3];             // 32000
  const int H = in_sizes[0] / BT;        // 1024
  const int nCB = V / 128;               // 250 column blocks

  char* ws = (char*)d_ws;
  const long wb_bytes = (long)V * H;     // fp8: 1 B/elem
  const long xb_bytes = (long)BT * H;
  char* Wf = ws;
  char* Xf = ws + wb_bytes;
  float* partials = (float*)(ws + wb_bytes + xb_bytes);
  float* xy = partials + (long)nCB * BT;
  float* bsum = xy + BT;
  float* bcnt = bsum + (BT / 64);

  cast_swz_k<<<8192, 256, 0, stream>>>(w, (uint4*)Wf, (long)V * H / 16);
  cast_swz_k<<<1024, 256, 0, stream>>>(x, (uint4*)Xf, (long)BT * H / 16);
  xy_k<<<BT, 256, 0, stream>>>(x, w, bias, tgt, xy, H, V);
  // grid.x = row-blocks (fast-varying) so consecutive blocks share the W tile in L2
  dim3 grid(BT / 256, nCB);
  gemm_sumexp<<<grid, 256, 0, stream>>>(Xf, Wf, bias, partials, H, BT);
  row_reduce<<<BT / 64, 256, 0, stream>>>(partials, xy, tgt, bsum, bcnt, BT, nCB);
  finalize<<<1, 64, 0, stream>>>(bsum, bcnt, out, BT / 64);
}

// Round 5
// 380.205 us; speedup vs baseline: 1.6702x; 1.6702x over previous
//
#include <hip/hip_runtime.h>
#include <hip/hip_bf16.h>
#include <stdint.h>

// FusedLinearCrossEntropyLoss on MI355X (gfx950)
// loss = mean_i( logsumexp_j(x_i . w_j + b_j) - (x_i . w_t(i) + b_t(i)) )
//
// R10: R6's proven no-LDS gemm (167us, VGPR 84, no spill) + ONE change:
//      XCD-PINNED M-SLAB GRID MAPPING.
//      Diagnosis: R6-R8 all latency-bound (period ~3200cy vs 1360cy matrix
//      work) at 2 waves/SIMD; R6 FETCH=135MB vs 36MB unique fp8 => W misses
//      L2+L3 (fp32 cast/xy churn evicts it); default dispatch spreads one W
//      panel's 16 row-blocks over all 8 XCDs and X (4MB) thrashes each 4MB L2.
//      Mapping: d = linear block id; xcd = d&7; j = d>>3; by = j>>1;
//      bx = xcd*2 + (j&1). Per XCD: X-slab 512KB stays L2-resident; W panels
//      stream with cross-XCD L3 reuse. R9's reg-pipeline lesson: do NOT touch
//      the loop structure (spill cliff at 256 regs).
//
// Chunk layout: chunk c = R*16 + g (R = 32-row block, g = 64-wide k group).
// Within chunk: half h in {0,1}, lane l in 0..63, byte j in 0..15:
//   data[c*2048 + h*1024 + l*16 + j] = M[R*32 + (l&31)][g*64 + (l>>5)*32 + h*16 + j]

typedef float f16v __attribute__((ext_vector_type(16)));
typedef int v8i __attribute__((ext_vector_type(8)));

__device__ __forceinline__ unsigned pk_fp8(float4 v) {
  int w = 0;
  w = __builtin_amdgcn_cvt_pk_fp8_f32(v.x, v.y, w, false);  // bytes 0,1
  w = __builtin_amdgcn_cvt_pk_fp8_f32(v.z, v.w, w, true);   // bytes 2,3
  return (unsigned)w;
}

// fp32 [N x 1024] -> fp8 fragment-swizzled chunks. One thread = 16 out bytes.
__global__ __launch_bounds__(256) void cast_swz_k(const float* __restrict__ in,
                                                  uint4* __restrict__ out,
                                                  long n16) {
  long t = (long)blockIdx.x * blockDim.x + threadIdx.x;
  long stride = (long)gridDim.x * blockDim.x;
  for (; t < n16; t += stride) {
    long o = t * 16;
    int c = (int)(o >> 11);
    int rem = (int)(o & 2047);
    int h = rem >> 10;
    int lam = (rem >> 4) & 63;
    int row = (c >> 4) * 32 + (lam & 31);
    int k = (c & 15) * 64 + (lam >> 5) * 32 + h * 16;
    const float4* src = (const float4*)(in + (long)row * 1024 + k);
    uint4 oo;
    oo.x = pk_fp8(src[0]); oo.y = pk_fp8(src[1]);
    oo.z = pk_fp8(src[2]); oo.w = pk_fp8(src[3]);
    out[t] = oo;
  }
}

// One block per row: x_y[row] = x[row] . W[safe_t] + bias[safe_t]  (fp32, exact)
__global__ __launch_bounds__(256) void xy_k(const float* __restrict__ x,
                                            const float* __restrict__ w,
                                            const float* __restrict__ bias,
                                            const int* __restrict__ tgt,
                                            float* __restrict__ xy, int H, int V) {
  int row = blockIdx.x;
  int t = tgt[row];
  int st = min(max(t, 0), V - 1);
  const float4* xr = (const float4*)(x + (long)row * H);
  const float4* wr = (const float4*)(w + (long)st * H);
  float s = 0.f;
  int n4 = H >> 2;
  for (int i = threadIdx.x; i < n4; i += 256) {
    float4 a = xr[i], b = wr[i];
    s += a.x * b.x + a.y * b.y + a.z * b.z + a.w * b.w;
  }
  for (int off = 32; off; off >>= 1) s += __shfl_down(s, off, 64);
  __shared__ float sm[4];
  if ((threadIdx.x & 63) == 0) sm[threadIdx.x >> 6] = s;
  __syncthreads();
  if (threadIdx.x == 0) xy[row] = sm[0] + sm[1] + sm[2] + sm[3] + bias[st];
}

// 256x128 block tile, 4 waves in 2x2; each wave 128x64 via 4x2 of 32x32x64.
// All operands loaded straight from global fragment chunks (no LDS staging).
// Epilogue: partials[by][row] = sum_cols exp(logit + bias).
__global__ __launch_bounds__(256, 2)
void gemm_sumexp(const char* __restrict__ Xf, const char* __restrict__ Wf,
                 const float* __restrict__ bias, float* __restrict__ partials,
                 int H, int BT) {
  __shared__ float rowsum[2][256];

  const int tid = threadIdx.x;
  const int w = tid >> 6, lane = tid & 63;
  const int wr = w >> 1, wc = w & 1;
  const int l32 = lane & 31, kh = lane >> 5;

  // XCD-pinned M-slab mapping (assumes round-robin XCD dispatch, d&7).
  // XCD k owns bx in {k*sl .. k*sl+sl-1} across ALL by panels:
  //   per-XCD X working set = sl*256 rows * 1KB = 512KB (L2-resident),
  //   W panels stream through L2 with cross-XCD L3 reuse.
  const int nbx = gridDim.x;
  const int d = blockIdx.y * nbx + blockIdx.x;
  int bx, by;
  if ((nbx & 7) == 0) {
    const int sl = nbx >> 3;          // slabs per XCD (16/8 = 2)
    const int xcd = d & 7;
    const int j = d >> 3;
    bx = xcd * sl + (j % sl);
    by = j / sl;
  } else {
    bx = blockIdx.x;
    by = blockIdx.y;
  }
  const int m0 = bx * 256, n0 = by * 128;

  f16v acc[4][2];
#pragma unroll
  for (int mi = 0; mi < 4; mi++)
#pragma unroll
    for (int ni = 0; ni < 2; ni++)
#pragma unroll
      for (int r = 0; r < 16; r++) acc[mi][ni][r] = 0.f;

  const int Rb = bx * 8 + wr * 4;   // A 32-row block base
  const int Nb = by * 4 + wc * 2;   // B 32-row block base

  const char* pa[4];
  const char* pb[2];
#pragma unroll
  for (int mi = 0; mi < 4; mi++)
    pa[mi] = Xf + ((long)(Rb + mi) * 16) * 2048 + lane * 16;
#pragma unroll
  for (int ni = 0; ni < 2; ni++)
    pb[ni] = Wf + ((long)(Nb + ni) * 16) * 2048 + lane * 16;

  const int nG = H >> 6;  // 16 k-groups of 64
#pragma unroll 4
  for (int g = 0; g < nG; g++) {
    v8i a[4], b[2];
#pragma unroll
    for (int mi = 0; mi < 4; mi++) {
      int4 lo = *(const int4*)(pa[mi]);
      int4 hi = *(const int4*)(pa[mi] + 1024);
      v8i t;
      t[0] = lo.x; t[1] = lo.y; t[2] = lo.z; t[3] = lo.w;
      t[4] = hi.x; t[5] = hi.y; t[6] = hi.z; t[7] = hi.w;
      a[mi] = t;
      pa[mi] += 2048;
    }
#pragma unroll
    for (int ni = 0; ni < 2; ni++) {
      int4 lo = *(const int4*)(pb[ni]);
      int4 hi = *(const int4*)(pb[ni] + 1024);
      v8i t;
      t[0] = lo.x; t[1] = lo.y; t[2] = lo.z; t[3] = lo.w;
      t[4] = hi.x; t[5] = hi.y; t[6] = hi.z; t[7] = hi.w;
      b[ni] = t;
      pb[ni] += 2048;
    }
#pragma unroll
    for (int mi = 0; mi < 4; mi++)
#pragma unroll
      for (int ni = 0; ni < 2; ni++)
        acc[mi][ni] = __builtin_amdgcn_mfma_scale_f32_32x32x64_f8f6f4(
            a[mi], b[ni], acc[mi][ni], 0 /*A=fp8*/, 0 /*B=fp8*/,
            0, 127 /*scale_a = 1.0*/, 0, 127 /*scale_b = 1.0*/);
  }

  // ---- epilogue: per-row sum of exp(logit + bias) ----
  // C/D 32x32 layout: col = lane&31, row = (reg&3) + 8*(reg>>2) + 4*(lane>>5)
  float bv[2];
  bv[0] = bias[n0 + wc * 64 + l32];
  bv[1] = bias[n0 + wc * 64 + 32 + l32];

#pragma unroll
  for (int mi = 0; mi < 4; mi++) {
    float p[16];
#pragma unroll
    for (int r = 0; r < 16; r++) p[r] = 0.f;
#pragma unroll
    for (int ni = 0; ni < 2; ni++)
#pragma unroll
      for (int r = 0; r < 16; r++) p[r] += __expf(acc[mi][ni][r] + bv[ni]);
    // reduce across the 32 columns (lanes within each 32-group)
#pragma unroll
    for (int off = 1; off < 32; off <<= 1)
#pragma unroll
      for (int r = 0; r < 16; r++) p[r] += __shfl_xor(p[r], off, 32);
    if (l32 == 0) {
#pragma unroll
      for (int r = 0; r < 16; r++)
        rowsum[wc][wr * 128 + mi * 32 + (r & 3) + 8 * (r >> 2) + 4 * kh] = p[r];
    }
  }
  __syncthreads();
  partials[(long)by * BT + m0 + tid] = rowsum[0][tid] + rowsum[1][tid];
}

// per-row: lse - x_y ; 4 threads per row for b-parallelism, 64 rows/block
__global__ __launch_bounds__(256)
void row_reduce(const float* __restrict__ partials, const float* __restrict__ xy,
                const int* __restrict__ tgt, float* __restrict__ bsum,
                float* __restrict__ bcnt, int BT, int nCB) {
  const int row = blockIdx.x * 64 + (threadIdx.x >> 2);
  const int q = threadIdx.x & 3;
  float S = 0.f;
  for (int b = q; b < nCB; b += 4) S += partials[(long)b * BT + row];
  S += __shfl_xor(S, 1, 64);
  S += __shfl_xor(S, 2, 64);
  float pr = 0.f, c = 0.f;
  if (q == 0) {
    int t = tgt[row];
    if (t != -100) { pr = logf(S) - xy[row]; c = 1.f; }
  }
  for (int off = 32; off; off >>= 1) {
    pr += __shfl_down(pr, off, 64);
    c += __shfl_down(c, off, 64);
  }
  __shared__ float sp[4], sc[4];
  if ((threadIdx.x & 63) == 0) {
    sp[threadIdx.x >> 6] = pr;
    sc[threadIdx.x >> 6] = c;
  }
  __syncthreads();
  if (threadIdx.x == 0) {
    bsum[blockIdx.x] = sp[0] + sp[1] + sp[2] + sp[3];
    bcnt[blockIdx.x] = sc[0] + sc[1] + sc[2] + sc[3];
  }
}

__global__ void finalize(const float* __restrict__ bsum, const float* __restrict__ bcnt,
                         float* __restrict__ out, int nb) {
  float s = 0.f, c = 0.f;
  for (int i = threadIdx.x; i < nb; i += 64) { s += bsum[i]; c += bcnt[i]; }
  for (int off = 32; off; off >>= 1) {
    s += __shfl_down(s, off, 64);
    c += __shfl_down(c, off, 64);
  }
  if (threadIdx.x == 0) out[0] = s / c;
}

extern "C" void kernel_launch(void* const* d_in, const int* in_sizes, int n_in,
                              void* d_out, int out_size, void* d_ws, size_t ws_size,
                              hipStream_t stream) {
  const float* x = (const float*)d_in[0];
  const int* tgt = (const int*)d_in[1];
  const float* w = (const float*)d_in[2];
  const float* bias = (const float*)d_in[3];
  float* out = (float*)d_out;

  const int BT = in_sizes[1];            // 4096
  const int V = in_sizes[3];             // 32000
  const int H = in_sizes[0] / BT;        // 1024
  const int nCB = V / 128;               // 250 column blocks

  char* ws = (char*)d_ws;
  const long wb_bytes = (long)V * H;     // fp8: 1 B/elem
  const long xb_bytes = (long)BT * H;
  char* Wf = ws;
  char* Xf = ws + wb_bytes;
  float* partials = (float*)(ws + wb_bytes + xb_bytes);
  float* xy = partials + (long)nCB * BT;
  float* bsum = xy + BT;
  float* bcnt = bsum + (BT / 64);

  cast_swz_k<<<8192, 256, 0, stream>>>(w, (uint4*)Wf, (long)V * H / 16);
  cast_swz_k<<<1024, 256, 0, stream>>>(x, (uint4*)Xf, (long)BT * H / 16);
  xy_k<<<BT, 256, 0, stream>>>(x, w, bias, tgt, xy, H, V);
  dim3 grid(BT / 256, nCB);
  gemm_sumexp<<<grid, 256, 0, stream>>>(Xf, Wf, bias, partials, H, BT);
  row_reduce<<<BT / 64, 256, 0, stream>>>(partials, xy, tgt, bsum, bcnt, BT, nCB);
  finalize<<<1, 64, 0, stream>>>(bsum, bcnt, out, BT / 64);
}